// Round 5
// baseline (104.517 us; speedup 1.0000x reference)
//
#include <hip/hip_runtime.h>
#include <hip/hip_bf16.h>

typedef __attribute__((ext_vector_type(4))) float f32x4;

#define TPB 256

// ---- ws layout (float offsets) ----
#define IN1F   0
#define IN2F   1120
#define HN1F   2240
#define HN2F   4288
#define L1OUT  6336
#define L3OUT  11456
#define GH1    16576
#define GH2    22720
#define GI1    28864
#define GI2    35008
#define H1OFF  41152
#define H2OFF  43200
#define T1OFF  45248
#define T2OFF  49344
// total 53440 floats = 213,760 bytes

// One block: stage x[0:K] (f32) into LDS, then 4 waves each compute NR rows
// CONCURRENTLY. K is now a COMPILE-TIME template parameter so the kc loop
// fully unrolls -> compiler clusters many independent global loads in flight
// (the round-2/3 runtime-K loop kept only ~2 loads outstanding -> 1.7 TB/s).
template <int K, int NR>
__device__ __forceinline__ void matvec_block(
    const float* __restrict__ W,
    const float* __restrict__ bias,
    const float* __restrict__ x, float* xl,
    int row0, float* __restrict__ y, int act)
{
    for (int i = threadIdx.x; i < (K >> 2); i += TPB)
        ((f32x4*)xl)[i] = ((const f32x4*)x)[i];
    __syncthreads();

    const int wid  = threadIdx.x >> 6;
    const int lane = threadIdx.x & 63;
    const int c0   = lane * 4;
    const int r0   = row0 + wid * NR;

    float acc[NR];
#pragma unroll
    for (int j = 0; j < NR; ++j) acc[j] = 0.f;

#pragma unroll
    for (int kc = 0; kc < K; kc += 256) {
        int c = kc + c0;
        if (c < K) {
            const f32x4 xv = *reinterpret_cast<const f32x4*>(xl + c);
#pragma unroll
            for (int j = 0; j < NR; ++j) {
                const f32x4 w4 =
                    *reinterpret_cast<const f32x4*>(W + (size_t)(r0 + j) * K + c);
                acc[j] += w4[0] * xv[0] + w4[1] * xv[1]
                        + w4[2] * xv[2] + w4[3] * xv[3];
            }
        }
    }
#pragma unroll
    for (int j = 0; j < NR; ++j) {
#pragma unroll
        for (int off = 32; off; off >>= 1) acc[j] += __shfl_xor(acc[j], off, 64);
    }
    if (lane == 0) {
#pragma unroll
        for (int j = 0; j < NR; ++j) {
            float v = acc[j] + bias[r0 + j];
            if (act) v = fmaxf(v, 0.f);
            y[r0 + j] = v;
        }
    }
}

// ---- stage 0: build input1/input2 + copy hn ----
__global__ void k_prep(const float* __restrict__ state_inno,
                       const float* __restrict__ obs_inno,
                       const float* __restrict__ diff_state,
                       const float* __restrict__ diff_obs,
                       const float* __restrict__ lin_err,
                       const float* __restrict__ jac,
                       const float* __restrict__ hn1,
                       const float* __restrict__ hn2,
                       float* __restrict__ ws)
{
    int i = blockIdx.x * blockDim.x + threadIdx.x;
    if (i < 1120) {
        float v;
        if (i < 32)       v = state_inno[i];
        else if (i < 64)  v = diff_state[i - 32];
        else if (i < 96)  v = lin_err[i - 64];
        else              v = jac[i - 96];
        ws[IN1F + i] = v;
        float v2;
        if (i < 32)       v2 = obs_inno[i];
        else if (i < 64)  v2 = diff_obs[i - 32];
        else              v2 = v;  // lin_err / jacobian shared
        ws[IN2F + i] = v2;
    }
    if (i < 2048) {
        ws[HN1F + i] = hn1[i];
        ws[HN2F + i] = hn2[i];
    }
}

// ---- stage A: l1, l3 (5120x1120, relu) + Whh@hn (6144x2048) x2 ----
// 8 rows/block: grid = 640 + 640 + 768 + 768 = 2816
__global__ void __launch_bounds__(TPB)
k_stageA(const float* l1_W, const float* l1_b,
         const float* l3_W, const float* l3_b,
         const float* Whh1, const float* bhh1,
         const float* Whh2, const float* bhh2,
         float* ws)
{
    __shared__ float xl[2048];
    int bid = blockIdx.x;
    if (bid < 640)
        matvec_block<1120, 2>(l1_W, l1_b, ws + IN1F, xl, bid * 8, ws + L1OUT, 1);
    else if (bid < 1280)
        matvec_block<1120, 2>(l3_W, l3_b, ws + IN2F, xl, (bid - 640) * 8, ws + L3OUT, 1);
    else if (bid < 2048)
        matvec_block<2048, 2>(Whh1, bhh1, ws + HN1F, xl, (bid - 1280) * 8, ws + GH1, 0);
    else
        matvec_block<2048, 2>(Whh2, bhh2, ws + HN2F, xl, (bid - 2048) * 8, ws + GH2, 0);
}

// ---- stage B: Wih @ l_out (6144x5120) x2 ----
// 8 rows/block: grid = 768 + 768 = 1536
__global__ void __launch_bounds__(TPB)
k_stageB(const float* Wih1, const float* bih1,
         const float* Wih2, const float* bih2,
         float* ws)
{
    __shared__ float xl[5120];
    int bid = blockIdx.x;
    if (bid < 768)
        matvec_block<5120, 2>(Wih1, bih1, ws + L1OUT, xl, bid * 8, ws + GI1, 0);
    else
        matvec_block<5120, 2>(Wih2, bih2, ws + L3OUT, xl, (bid - 768) * 8, ws + GI2, 0);
}

// ---- stage C: GRU gate combine (both branches) ----
__global__ void k_gru(const float* __restrict__ hn1,
                      const float* __restrict__ hn2,
                      float* __restrict__ ws)
{
    int i = blockIdx.x * blockDim.x + threadIdx.x;  // 0..4095
    int b = i >> 11, j = i & 2047;
    const float* gi = ws + (b ? GI2 : GI1);
    const float* gh = ws + (b ? GH2 : GH1);
    const float* hn = b ? hn2 : hn1;
    float r = 1.f / (1.f + expf(-(gi[j] + gh[j])));
    float z = 1.f / (1.f + expf(-(gi[2048 + j] + gh[2048 + j])));
    float n = tanhf(gi[4096 + j] + r * gh[4096 + j]);
    float h = (1.f - z) * n + z * hn[j];
    ws[(b ? H2OFF : H1OFF) + j] = h;
}

// ---- stage D: l2_W1 / l4_W1 (4096x2048, relu) ----
// 8 rows/block: grid = 512 + 512 = 1024
__global__ void __launch_bounds__(TPB)
k_stageD(const float* W21, const float* b21,
         const float* W41, const float* b41,
         float* ws)
{
    __shared__ float xl[2048];
    int bid = blockIdx.x;
    if (bid < 512)
        matvec_block<2048, 2>(W21, b21, ws + H1OFF, xl, bid * 8, ws + T1OFF, 1);
    else
        matvec_block<2048, 2>(W41, b41, ws + H2OFF, xl, (bid - 512) * 8, ws + T2OFF, 1);
}

// ---- stage E: l2_W2 / l4_W2 (1024x4096) -> f32 out ----
// One ROW per block; 4 waves split K=4096 into quarters. grid = 2048.
__global__ void __launch_bounds__(TPB)
k_stageE(const float* __restrict__ W22, const float* __restrict__ b22,
         const float* __restrict__ W42, const float* __restrict__ b42,
         const float* __restrict__ ws, float* __restrict__ out)
{
    __shared__ float part[4];
    int r = blockIdx.x;  // 0..2047
    const float* W; const float* b; const float* x; int rr;
    if (r < 1024) { W = W22; b = b22; x = ws + T1OFF; rr = r; }
    else          { W = W42; b = b42; x = ws + T2OFF; rr = r - 1024; }

    const int wid  = threadIdx.x >> 6;
    const int lane = threadIdx.x & 63;
    const float* Wr = W + (size_t)rr * 4096 + wid * 1024;
    const float* xw = x + wid * 1024;
    const int c0 = lane * 4;

    float acc = 0.f;
#pragma unroll
    for (int kc = 0; kc < 1024; kc += 256) {
        const f32x4 w4 = *reinterpret_cast<const f32x4*>(Wr + kc + c0);
        const f32x4 xv = *reinterpret_cast<const f32x4*>(xw + kc + c0);
        acc += w4[0] * xv[0] + w4[1] * xv[1] + w4[2] * xv[2] + w4[3] * xv[3];
    }
#pragma unroll
    for (int off = 32; off; off >>= 1) acc += __shfl_xor(acc, off, 64);
    if (lane == 0) part[wid] = acc;
    __syncthreads();
    if (threadIdx.x == 0)
        out[r] = part[0] + part[1] + part[2] + part[3] + b[rr];
}

extern "C" void kernel_launch(void* const* d_in, const int* in_sizes, int n_in,
                              void* d_out, int out_size, void* d_ws, size_t ws_size,
                              hipStream_t stream)
{
    const float* state_inno = (const float*)d_in[0];
    const float* obs_inno   = (const float*)d_in[1];
    const float* diff_state = (const float*)d_in[2];
    const float* diff_obs   = (const float*)d_in[3];
    const float* lin_err    = (const float*)d_in[4];
    const float* jac        = (const float*)d_in[5];
    const float* l1_W  = (const float*)d_in[6];
    const float* l1_b  = (const float*)d_in[7];
    const float* g1Wih = (const float*)d_in[8];
    const float* g1Whh = (const float*)d_in[9];
    const float* g1bih = (const float*)d_in[10];
    const float* g1bhh = (const float*)d_in[11];
    const float* l2_W1 = (const float*)d_in[12];
    const float* l2_b1 = (const float*)d_in[13];
    const float* l2_W2 = (const float*)d_in[14];
    const float* l2_b2 = (const float*)d_in[15];
    const float* l3_W  = (const float*)d_in[16];
    const float* l3_b  = (const float*)d_in[17];
    const float* g2Wih = (const float*)d_in[18];
    const float* g2Whh = (const float*)d_in[19];
    const float* g2bih = (const float*)d_in[20];
    const float* g2bhh = (const float*)d_in[21];
    const float* l4_W1 = (const float*)d_in[22];
    const float* l4_b1 = (const float*)d_in[23];
    const float* l4_W2 = (const float*)d_in[24];
    const float* l4_b2 = (const float*)d_in[25];
    const float* hn1   = (const float*)d_in[26];
    const float* hn2   = (const float*)d_in[27];

    float* ws = (float*)d_ws;
    float* out = (float*)d_out;

    hipLaunchKernelGGL(k_prep, dim3(8), dim3(TPB), 0, stream,
                       state_inno, obs_inno, diff_state, diff_obs, lin_err, jac,
                       hn1, hn2, ws);

    hipLaunchKernelGGL(k_stageA, dim3(2816), dim3(TPB), 0, stream,
                       l1_W, l1_b, l3_W, l3_b, g1Whh, g1bhh, g2Whh, g2bhh, ws);

    hipLaunchKernelGGL(k_stageB, dim3(1536), dim3(TPB), 0, stream,
                       g1Wih, g1bih, g2Wih, g2bih, ws);

    hipLaunchKernelGGL(k_gru, dim3(16), dim3(TPB), 0, stream, hn1, hn2, ws);

    hipLaunchKernelGGL(k_stageD, dim3(1024), dim3(TPB), 0, stream,
                       l2_W1, l2_b1, l4_W1, l4_b1, ws);

    hipLaunchKernelGGL(k_stageE, dim3(2048), dim3(TPB), 0, stream,
                       l2_W2, l2_b2, l4_W2, l4_b2, ws, out);
}

// Round 6
// 102.487 us; speedup vs baseline: 1.0198x; 1.0198x over previous
//
#include <hip/hip_runtime.h>
#include <hip/hip_bf16.h>

typedef __attribute__((ext_vector_type(4))) float f32x4;

#define TPB 256

// ---- ws layout (float offsets) ----
#define IN1F   0
#define IN2F   1120
#define HN1F   2240
#define HN2F   4288
#define L1OUT  6336
#define L3OUT  11456
#define GH1    16576
#define GH2    22720
#define GI1    28864
#define GI2    35008
#define H1OFF  41152
#define H2OFF  43200
#define T1OFF  45248
#define T2OFF  49344
// total 53440 floats = 213,760 bytes

// One block: stage x[0:K] into LDS, then 4 waves each compute NR rows.
// Inner loop is BURST-BATCHED: per burst, issue NR*NB independent
// global_load_dwordx4 into a statically-indexed register array, then consume.
// (Round-5 codegen kept VGPR=36 -> ~1 load in flight -> 1.7 TB/s. This forces
// ~10 loads / 10KB in flight per wave, and 5KB-contiguous stream visits.)
template <int K, int NR, int NB>
__device__ __forceinline__ void matvec_block(
    const float* __restrict__ W,
    const float* __restrict__ bias,
    const float* __restrict__ x, float* xl,
    int row0, float* __restrict__ y, int act)
{
    for (int i = threadIdx.x; i < (K >> 2); i += TPB)
        ((f32x4*)xl)[i] = ((const f32x4*)x)[i];
    __syncthreads();

    const int wid  = threadIdx.x >> 6;
    const int lane = threadIdx.x & 63;
    const int c0   = lane * 4;
    const int r0   = row0 + wid * NR;
    const f32x4 vzero = {0.f, 0.f, 0.f, 0.f};

    constexpr int CH = (K + 255) / 256;   // 256-float chunks per row

    float acc[NR];
#pragma unroll
    for (int j = 0; j < NR; ++j) acc[j] = 0.f;

#pragma unroll
    for (int base = 0; base < CH; base += NB) {
        f32x4 wreg[NR][NB];
        // issue phase: NR*NB independent loads
#pragma unroll
        for (int s = 0; s < NB; ++s) {
            const int c = (base + s) * 256 + c0;
#pragma unroll
            for (int j = 0; j < NR; ++j) {
                wreg[j][s] = ((base + s) < CH && c < K)
                    ? *reinterpret_cast<const f32x4*>(W + (size_t)(r0 + j) * K + c)
                    : vzero;
            }
        }
        // consume phase
#pragma unroll
        for (int s = 0; s < NB; ++s) {
            const int c = (base + s) * 256 + c0;
            const f32x4 xv = ((base + s) < CH && c < K)
                ? *reinterpret_cast<const f32x4*>(xl + c) : vzero;
#pragma unroll
            for (int j = 0; j < NR; ++j)
                acc[j] += wreg[j][s][0] * xv[0] + wreg[j][s][1] * xv[1]
                        + wreg[j][s][2] * xv[2] + wreg[j][s][3] * xv[3];
        }
    }

#pragma unroll
    for (int j = 0; j < NR; ++j) {
#pragma unroll
        for (int off = 32; off; off >>= 1) acc[j] += __shfl_xor(acc[j], off, 64);
    }
    if (lane == 0) {
#pragma unroll
        for (int j = 0; j < NR; ++j) {
            float v = acc[j] + bias[r0 + j];
            if (act) v = fmaxf(v, 0.f);
            y[r0 + j] = v;
        }
    }
}

// ---- stage 0: build input1/input2 + copy hn ----
__global__ void k_prep(const float* __restrict__ state_inno,
                       const float* __restrict__ obs_inno,
                       const float* __restrict__ diff_state,
                       const float* __restrict__ diff_obs,
                       const float* __restrict__ lin_err,
                       const float* __restrict__ jac,
                       const float* __restrict__ hn1,
                       const float* __restrict__ hn2,
                       float* __restrict__ ws)
{
    int i = blockIdx.x * blockDim.x + threadIdx.x;
    if (i < 1120) {
        float v;
        if (i < 32)       v = state_inno[i];
        else if (i < 64)  v = diff_state[i - 32];
        else if (i < 96)  v = lin_err[i - 64];
        else              v = jac[i - 96];
        ws[IN1F + i] = v;
        float v2;
        if (i < 32)       v2 = obs_inno[i];
        else if (i < 64)  v2 = diff_obs[i - 32];
        else              v2 = v;  // lin_err / jacobian shared
        ws[IN2F + i] = v2;
    }
    if (i < 2048) {
        ws[HN1F + i] = hn1[i];
        ws[HN2F + i] = hn2[i];
    }
}

// ---- stage A: l1, l3 (5120x1120, relu) + Whh@hn (6144x2048) x2 ----
// 8 rows/block: grid = 640 + 640 + 768 + 768 = 2816
__global__ void __launch_bounds__(TPB)
k_stageA(const float* l1_W, const float* l1_b,
         const float* l3_W, const float* l3_b,
         const float* Whh1, const float* bhh1,
         const float* Whh2, const float* bhh2,
         float* ws)
{
    __shared__ float xl[2048];
    int bid = blockIdx.x;
    if (bid < 640)
        matvec_block<1120, 2, 5>(l1_W, l1_b, ws + IN1F, xl, bid * 8, ws + L1OUT, 1);
    else if (bid < 1280)
        matvec_block<1120, 2, 5>(l3_W, l3_b, ws + IN2F, xl, (bid - 640) * 8, ws + L3OUT, 1);
    else if (bid < 2048)
        matvec_block<2048, 2, 4>(Whh1, bhh1, ws + HN1F, xl, (bid - 1280) * 8, ws + GH1, 0);
    else
        matvec_block<2048, 2, 4>(Whh2, bhh2, ws + HN2F, xl, (bid - 2048) * 8, ws + GH2, 0);
}

// ---- stage B: Wih @ l_out (6144x5120) x2 ----
// 8 rows/block: grid = 768 + 768 = 1536
__global__ void __launch_bounds__(TPB)
k_stageB(const float* Wih1, const float* bih1,
         const float* Wih2, const float* bih2,
         float* ws)
{
    __shared__ float xl[5120];
    int bid = blockIdx.x;
    if (bid < 768)
        matvec_block<5120, 2, 5>(Wih1, bih1, ws + L1OUT, xl, bid * 8, ws + GI1, 0);
    else
        matvec_block<5120, 2, 5>(Wih2, bih2, ws + L3OUT, xl, (bid - 768) * 8, ws + GI2, 0);
}

// ---- stage C: GRU gate combine (both branches) ----
__global__ void k_gru(const float* __restrict__ hn1,
                      const float* __restrict__ hn2,
                      float* __restrict__ ws)
{
    int i = blockIdx.x * blockDim.x + threadIdx.x;  // 0..4095
    int b = i >> 11, j = i & 2047;
    const float* gi = ws + (b ? GI2 : GI1);
    const float* gh = ws + (b ? GH2 : GH1);
    const float* hn = b ? hn2 : hn1;
    float r = 1.f / (1.f + expf(-(gi[j] + gh[j])));
    float z = 1.f / (1.f + expf(-(gi[2048 + j] + gh[2048 + j])));
    float n = tanhf(gi[4096 + j] + r * gh[4096 + j]);
    float h = (1.f - z) * n + z * hn[j];
    ws[(b ? H2OFF : H1OFF) + j] = h;
}

// ---- stage D: l2_W1 / l4_W1 (4096x2048, relu) ----
// 8 rows/block: grid = 512 + 512 = 1024
__global__ void __launch_bounds__(TPB)
k_stageD(const float* W21, const float* b21,
         const float* W41, const float* b41,
         float* ws)
{
    __shared__ float xl[2048];
    int bid = blockIdx.x;
    if (bid < 512)
        matvec_block<2048, 2, 4>(W21, b21, ws + H1OFF, xl, bid * 8, ws + T1OFF, 1);
    else
        matvec_block<2048, 2, 4>(W41, b41, ws + H2OFF, xl, (bid - 512) * 8, ws + T2OFF, 1);
}

// ---- stage E: l2_W2 / l4_W2 (1024x4096) -> f32 out ----
// One ROW per block; 4 waves split K=4096 into quarters; batched 4-load burst.
__global__ void __launch_bounds__(TPB)
k_stageE(const float* __restrict__ W22, const float* __restrict__ b22,
         const float* __restrict__ W42, const float* __restrict__ b42,
         const float* __restrict__ ws, float* __restrict__ out)
{
    __shared__ float part[4];
    int r = blockIdx.x;  // 0..2047
    const float* W; const float* b; const float* x; int rr;
    if (r < 1024) { W = W22; b = b22; x = ws + T1OFF; rr = r; }
    else          { W = W42; b = b42; x = ws + T2OFF; rr = r - 1024; }

    const int wid  = threadIdx.x >> 6;
    const int lane = threadIdx.x & 63;
    const float* Wr = W + (size_t)rr * 4096 + wid * 1024;
    const float* xw = x + wid * 1024;
    const int c0 = lane * 4;

    f32x4 wreg[4];
#pragma unroll
    for (int s = 0; s < 4; ++s)
        wreg[s] = *reinterpret_cast<const f32x4*>(Wr + s * 256 + c0);

    float acc = 0.f;
#pragma unroll
    for (int s = 0; s < 4; ++s) {
        const f32x4 xv = *reinterpret_cast<const f32x4*>(xw + s * 256 + c0);
        acc += wreg[s][0] * xv[0] + wreg[s][1] * xv[1]
             + wreg[s][2] * xv[2] + wreg[s][3] * xv[3];
    }
#pragma unroll
    for (int off = 32; off; off >>= 1) acc += __shfl_xor(acc, off, 64);
    if (lane == 0) part[wid] = acc;
    __syncthreads();
    if (threadIdx.x == 0)
        out[r] = part[0] + part[1] + part[2] + part[3] + b[rr];
}

extern "C" void kernel_launch(void* const* d_in, const int* in_sizes, int n_in,
                              void* d_out, int out_size, void* d_ws, size_t ws_size,
                              hipStream_t stream)
{
    const float* state_inno = (const float*)d_in[0];
    const float* obs_inno   = (const float*)d_in[1];
    const float* diff_state = (const float*)d_in[2];
    const float* diff_obs   = (const float*)d_in[3];
    const float* lin_err    = (const float*)d_in[4];
    const float* jac        = (const float*)d_in[5];
    const float* l1_W  = (const float*)d_in[6];
    const float* l1_b  = (const float*)d_in[7];
    const float* g1Wih = (const float*)d_in[8];
    const float* g1Whh = (const float*)d_in[9];
    const float* g1bih = (const float*)d_in[10];
    const float* g1bhh = (const float*)d_in[11];
    const float* l2_W1 = (const float*)d_in[12];
    const float* l2_b1 = (const float*)d_in[13];
    const float* l2_W2 = (const float*)d_in[14];
    const float* l2_b2 = (const float*)d_in[15];
    const float* l3_W  = (const float*)d_in[16];
    const float* l3_b  = (const float*)d_in[17];
    const float* g2Wih = (const float*)d_in[18];
    const float* g2Whh = (const float*)d_in[19];
    const float* g2bih = (const float*)d_in[20];
    const float* g2bhh = (const float*)d_in[21];
    const float* l4_W1 = (const float*)d_in[22];
    const float* l4_b1 = (const float*)d_in[23];
    const float* l4_W2 = (const float*)d_in[24];
    const float* l4_b2 = (const float*)d_in[25];
    const float* hn1   = (const float*)d_in[26];
    const float* hn2   = (const float*)d_in[27];

    float* ws = (float*)d_ws;
    float* out = (float*)d_out;

    hipLaunchKernelGGL(k_prep, dim3(8), dim3(TPB), 0, stream,
                       state_inno, obs_inno, diff_state, diff_obs, lin_err, jac,
                       hn1, hn2, ws);

    hipLaunchKernelGGL(k_stageA, dim3(2816), dim3(TPB), 0, stream,
                       l1_W, l1_b, l3_W, l3_b, g1Whh, g1bhh, g2Whh, g2bhh, ws);

    hipLaunchKernelGGL(k_stageB, dim3(1536), dim3(TPB), 0, stream,
                       g1Wih, g1bih, g2Wih, g2bih, ws);

    hipLaunchKernelGGL(k_gru, dim3(16), dim3(TPB), 0, stream, hn1, hn2, ws);

    hipLaunchKernelGGL(k_stageD, dim3(1024), dim3(TPB), 0, stream,
                       l2_W1, l2_b1, l4_W1, l4_b1, ws);

    hipLaunchKernelGGL(k_stageE, dim3(2048), dim3(TPB), 0, stream,
                       l2_W2, l2_b2, l4_W2, l4_b2, ws, out);
}

// Round 7
// 102.013 us; speedup vs baseline: 1.0245x; 1.0047x over previous
//
#include <hip/hip_runtime.h>
#include <hip/hip_bf16.h>

typedef __attribute__((ext_vector_type(4))) float f32x4;

#define TPB 256

// ---- ws layout (float offsets) ----
#define IN1F   0
#define IN2F   1120
#define HN1F   2240
#define HN2F   4288
#define L1OUT  6336
#define L3OUT  11456
#define GH1    16576
#define GH2    22720
#define GI1    28864
#define GI2    35008
#define H1OFF  41152
#define H2OFF  43200
#define T1OFF  45248
#define T2OFF  49344
// total 53440 floats = 213,760 bytes

// 8 back-to-back global_load_dwordx4 in ONE asm block (2 rows x 4KB), with
// the vmcnt(0) drain inside the block -> outputs valid at block end.
// Rounds 5/6 proved the scheduler sinks source-level load batches (VGPR
// stayed 36 -> 1 load in flight -> 1.7 TB/s); asm is exempt from that.
__device__ __forceinline__ void burst8(
    const float* a0, const float* a1,
    f32x4& w00, f32x4& w01, f32x4& w02, f32x4& w03,
    f32x4& w10, f32x4& w11, f32x4& w12, f32x4& w13)
{
    asm volatile(
        "global_load_dwordx4 %0, %8, off\n\t"
        "global_load_dwordx4 %1, %8, off offset:1024\n\t"
        "global_load_dwordx4 %2, %8, off offset:2048\n\t"
        "global_load_dwordx4 %3, %8, off offset:3072\n\t"
        "global_load_dwordx4 %4, %9, off\n\t"
        "global_load_dwordx4 %5, %9, off offset:1024\n\t"
        "global_load_dwordx4 %6, %9, off offset:2048\n\t"
        "global_load_dwordx4 %7, %9, off offset:3072\n\t"
        "s_waitcnt vmcnt(0)"
        : "=&v"(w00), "=&v"(w01), "=&v"(w02), "=&v"(w03),
          "=&v"(w10), "=&v"(w11), "=&v"(w12), "=&v"(w13)
        : "v"(a0), "v"(a1)
        : "memory");
}

// One block: stage x[0:K] into LDS; 4 waves x 2 rows each (8 rows/block).
// Main loop: asm 8-load bursts (4KB per row per burst). Tail (K%1024) in HIP.
template <int K>
__device__ __forceinline__ void matvec_asm(
    const float* __restrict__ W, const float* __restrict__ bias,
    const float* __restrict__ x, float* xl,
    int row0, float* __restrict__ y, int act)
{
    for (int i = threadIdx.x; i < (K >> 2); i += TPB)
        ((f32x4*)xl)[i] = ((const f32x4*)x)[i];
    __syncthreads();

    const int wid  = threadIdx.x >> 6;
    const int lane = threadIdx.x & 63;
    const int c0   = lane * 4;
    const int r0   = row0 + wid * 2;

    const float* Wr0 = W + (size_t)r0 * K + c0;
    const float* Wr1 = Wr0 + K;

    float acc0 = 0.f, acc1 = 0.f;

    constexpr int NBUR = K / 1024;
#pragma unroll
    for (int b = 0; b < NBUR; ++b) {
        const int kc = b * 1024;
        f32x4 w00, w01, w02, w03, w10, w11, w12, w13;
        burst8(Wr0 + kc, Wr1 + kc, w00, w01, w02, w03, w10, w11, w12, w13);
        {
            const f32x4 xv = *reinterpret_cast<const f32x4*>(xl + kc + c0);
            acc0 += w00[0]*xv[0] + w00[1]*xv[1] + w00[2]*xv[2] + w00[3]*xv[3];
            acc1 += w10[0]*xv[0] + w10[1]*xv[1] + w10[2]*xv[2] + w10[3]*xv[3];
        }
        {
            const f32x4 xv = *reinterpret_cast<const f32x4*>(xl + kc + 256 + c0);
            acc0 += w01[0]*xv[0] + w01[1]*xv[1] + w01[2]*xv[2] + w01[3]*xv[3];
            acc1 += w11[0]*xv[0] + w11[1]*xv[1] + w11[2]*xv[2] + w11[3]*xv[3];
        }
        {
            const f32x4 xv = *reinterpret_cast<const f32x4*>(xl + kc + 512 + c0);
            acc0 += w02[0]*xv[0] + w02[1]*xv[1] + w02[2]*xv[2] + w02[3]*xv[3];
            acc1 += w12[0]*xv[0] + w12[1]*xv[1] + w12[2]*xv[2] + w12[3]*xv[3];
        }
        {
            const f32x4 xv = *reinterpret_cast<const f32x4*>(xl + kc + 768 + c0);
            acc0 += w03[0]*xv[0] + w03[1]*xv[1] + w03[2]*xv[2] + w03[3]*xv[3];
            acc1 += w13[0]*xv[0] + w13[1]*xv[1] + w13[2]*xv[2] + w13[3]*xv[3];
        }
    }
    constexpr int TK = K - NBUR * 1024;
    if constexpr (TK > 0) {
        const int kc = NBUR * 1024;
        if (c0 < TK) {
            const f32x4 xv = *reinterpret_cast<const f32x4*>(xl + kc + c0);
            const f32x4 w0 = *reinterpret_cast<const f32x4*>(Wr0 + kc);
            const f32x4 w1 = *reinterpret_cast<const f32x4*>(Wr1 + kc);
            acc0 += w0[0]*xv[0] + w0[1]*xv[1] + w0[2]*xv[2] + w0[3]*xv[3];
            acc1 += w1[0]*xv[0] + w1[1]*xv[1] + w1[2]*xv[2] + w1[3]*xv[3];
        }
    }

#pragma unroll
    for (int off = 32; off; off >>= 1) {
        acc0 += __shfl_xor(acc0, off, 64);
        acc1 += __shfl_xor(acc1, off, 64);
    }
    if (lane == 0) {
        float v0 = acc0 + bias[r0];
        float v1 = acc1 + bias[r0 + 1];
        if (act) { v0 = fmaxf(v0, 0.f); v1 = fmaxf(v1, 0.f); }
        y[r0]     = v0;
        y[r0 + 1] = v1;
    }
}

// ---- stage 0: build input1/input2 + copy hn ----
__global__ void k_prep(const float* __restrict__ state_inno,
                       const float* __restrict__ obs_inno,
                       const float* __restrict__ diff_state,
                       const float* __restrict__ diff_obs,
                       const float* __restrict__ lin_err,
                       const float* __restrict__ jac,
                       const float* __restrict__ hn1,
                       const float* __restrict__ hn2,
                       float* __restrict__ ws)
{
    int i = blockIdx.x * blockDim.x + threadIdx.x;
    if (i < 1120) {
        float v;
        if (i < 32)       v = state_inno[i];
        else if (i < 64)  v = diff_state[i - 32];
        else if (i < 96)  v = lin_err[i - 64];
        else              v = jac[i - 96];
        ws[IN1F + i] = v;
        float v2;
        if (i < 32)       v2 = obs_inno[i];
        else if (i < 64)  v2 = diff_obs[i - 32];
        else              v2 = v;  // lin_err / jacobian shared
        ws[IN2F + i] = v2;
    }
    if (i < 2048) {
        ws[HN1F + i] = hn1[i];
        ws[HN2F + i] = hn2[i];
    }
}

// ---- stage A: l1, l3 (5120x1120, relu) + Whh@hn (6144x2048) x2 ----
// 8 rows/block: grid = 640 + 640 + 768 + 768 = 2816
__global__ void __launch_bounds__(TPB)
k_stageA(const float* l1_W, const float* l1_b,
         const float* l3_W, const float* l3_b,
         const float* Whh1, const float* bhh1,
         const float* Whh2, const float* bhh2,
         float* ws)
{
    __shared__ float xl[2048];
    int bid = blockIdx.x;
    if (bid < 640)
        matvec_asm<1120>(l1_W, l1_b, ws + IN1F, xl, bid * 8, ws + L1OUT, 1);
    else if (bid < 1280)
        matvec_asm<1120>(l3_W, l3_b, ws + IN2F, xl, (bid - 640) * 8, ws + L3OUT, 1);
    else if (bid < 2048)
        matvec_asm<2048>(Whh1, bhh1, ws + HN1F, xl, (bid - 1280) * 8, ws + GH1, 0);
    else
        matvec_asm<2048>(Whh2, bhh2, ws + HN2F, xl, (bid - 2048) * 8, ws + GH2, 0);
}

// ---- stage B: Wih @ l_out (6144x5120) x2 ----
// 8 rows/block: grid = 768 + 768 = 1536
__global__ void __launch_bounds__(TPB)
k_stageB(const float* Wih1, const float* bih1,
         const float* Wih2, const float* bih2,
         float* ws)
{
    __shared__ float xl[5120];
    int bid = blockIdx.x;
    if (bid < 768)
        matvec_asm<5120>(Wih1, bih1, ws + L1OUT, xl, bid * 8, ws + GI1, 0);
    else
        matvec_asm<5120>(Wih2, bih2, ws + L3OUT, xl, (bid - 768) * 8, ws + GI2, 0);
}

// ---- stage C: GRU gate combine (both branches) ----
__global__ void k_gru(const float* __restrict__ hn1,
                      const float* __restrict__ hn2,
                      float* __restrict__ ws)
{
    int i = blockIdx.x * blockDim.x + threadIdx.x;  // 0..4095
    int b = i >> 11, j = i & 2047;
    const float* gi = ws + (b ? GI2 : GI1);
    const float* gh = ws + (b ? GH2 : GH1);
    const float* hn = b ? hn2 : hn1;
    float r = 1.f / (1.f + expf(-(gi[j] + gh[j])));
    float z = 1.f / (1.f + expf(-(gi[2048 + j] + gh[2048 + j])));
    float n = tanhf(gi[4096 + j] + r * gh[4096 + j]);
    float h = (1.f - z) * n + z * hn[j];
    ws[(b ? H2OFF : H1OFF) + j] = h;
}

// ---- stage D: l2_W1 / l4_W1 (4096x2048, relu) ----
// 8 rows/block: grid = 512 + 512 = 1024
__global__ void __launch_bounds__(TPB)
k_stageD(const float* W21, const float* b21,
         const float* W41, const float* b41,
         float* ws)
{
    __shared__ float xl[2048];
    int bid = blockIdx.x;
    if (bid < 512)
        matvec_asm<2048>(W21, b21, ws + H1OFF, xl, bid * 8, ws + T1OFF, 1);
    else
        matvec_asm<2048>(W41, b41, ws + H2OFF, xl, (bid - 512) * 8, ws + T2OFF, 1);
}

// ---- stage E: l2_W2 / l4_W2 (1024x4096) -> f32 out ----
// One ROW per block; 4 waves split K=4096 into quarters. grid = 2048.
__global__ void __launch_bounds__(TPB)
k_stageE(const float* __restrict__ W22, const float* __restrict__ b22,
         const float* __restrict__ W42, const float* __restrict__ b42,
         const float* __restrict__ ws, float* __restrict__ out)
{
    __shared__ float part[4];
    int r = blockIdx.x;  // 0..2047
    const float* W; const float* b; const float* x; int rr;
    if (r < 1024) { W = W22; b = b22; x = ws + T1OFF; rr = r; }
    else          { W = W42; b = b42; x = ws + T2OFF; rr = r - 1024; }

    const int wid  = threadIdx.x >> 6;
    const int lane = threadIdx.x & 63;
    const float* Wr = W + (size_t)rr * 4096 + wid * 1024;
    const float* xw = x + wid * 1024;
    const int c0 = lane * 4;

    f32x4 wreg[4];
#pragma unroll
    for (int s = 0; s < 4; ++s)
        wreg[s] = *reinterpret_cast<const f32x4*>(Wr + s * 256 + c0);

    float acc = 0.f;
#pragma unroll
    for (int s = 0; s < 4; ++s) {
        const f32x4 xv = *reinterpret_cast<const f32x4*>(xw + s * 256 + c0);
        acc += wreg[s][0] * xv[0] + wreg[s][1] * xv[1]
             + wreg[s][2] * xv[2] + wreg[s][3] * xv[3];
    }
#pragma unroll
    for (int off = 32; off; off >>= 1) acc += __shfl_xor(acc, off, 64);
    if (lane == 0) part[wid] = acc;
    __syncthreads();
    if (threadIdx.x == 0)
        out[r] = part[0] + part[1] + part[2] + part[3] + b[rr];
}

extern "C" void kernel_launch(void* const* d_in, const int* in_sizes, int n_in,
                              void* d_out, int out_size, void* d_ws, size_t ws_size,
                              hipStream_t stream)
{
    const float* state_inno = (const float*)d_in[0];
    const float* obs_inno   = (const float*)d_in[1];
    const float* diff_state = (const float*)d_in[2];
    const float* diff_obs   = (const float*)d_in[3];
    const float* lin_err    = (const float*)d_in[4];
    const float* jac        = (const float*)d_in[5];
    const float* l1_W  = (const float*)d_in[6];
    const float* l1_b  = (const float*)d_in[7];
    const float* g1Wih = (const float*)d_in[8];
    const float* g1Whh = (const float*)d_in[9];
    const float* g1bih = (const float*)d_in[10];
    const float* g1bhh = (const float*)d_in[11];
    const float* l2_W1 = (const float*)d_in[12];
    const float* l2_b1 = (const float*)d_in[13];
    const float* l2_W2 = (const float*)d_in[14];
    const float* l2_b2 = (const float*)d_in[15];
    const float* l3_W  = (const float*)d_in[16];
    const float* l3_b  = (const float*)d_in[17];
    const float* g2Wih = (const float*)d_in[18];
    const float* g2Whh = (const float*)d_in[19];
    const float* g2bih = (const float*)d_in[20];
    const float* g2bhh = (const float*)d_in[21];
    const float* l4_W1 = (const float*)d_in[22];
    const float* l4_b1 = (const float*)d_in[23];
    const float* l4_W2 = (const float*)d_in[24];
    const float* l4_b2 = (const float*)d_in[25];
    const float* hn1   = (const float*)d_in[26];
    const float* hn2   = (const float*)d_in[27];

    float* ws = (float*)d_ws;
    float* out = (float*)d_out;

    hipLaunchKernelGGL(k_prep, dim3(8), dim3(TPB), 0, stream,
                       state_inno, obs_inno, diff_state, diff_obs, lin_err, jac,
                       hn1, hn2, ws);

    hipLaunchKernelGGL(k_stageA, dim3(2816), dim3(TPB), 0, stream,
                       l1_W, l1_b, l3_W, l3_b, g1Whh, g1bhh, g2Whh, g2bhh, ws);

    hipLaunchKernelGGL(k_stageB, dim3(1536), dim3(TPB), 0, stream,
                       g1Wih, g1bih, g2Wih, g2bih, ws);

    hipLaunchKernelGGL(k_gru, dim3(16), dim3(TPB), 0, stream, hn1, hn2, ws);

    hipLaunchKernelGGL(k_stageD, dim3(1024), dim3(TPB), 0, stream,
                       l2_W1, l2_b1, l4_W1, l4_b1, ws);

    hipLaunchKernelGGL(k_stageE, dim3(2048), dim3(TPB), 0, stream,
                       l2_W2, l2_b2, l4_W2, l4_b2, ws, out);
}